// Round 1
// baseline (385.678 us; speedup 1.0000x reference)
//
#include <hip/hip_runtime.h>
#include <cmath>

// HistorySAGE: 3-layer GraphSAGE (eval). Only rows < NN0=20000 of every
// intermediate are ever consumed by the final output (idx values < 20000,
// output rows < 20000), so all layers compute exactly 20000 rows.
constexpr int ROWS = 20000;
constexpr int BR   = 32;      // rows per block
constexpr float BN_EPS = 1e-5f;

template<int K, int NOUT, bool BNRELU>
__global__ __launch_bounds__(256)
void sage_layer(const float* __restrict__ src,
                const int*   __restrict__ ptr,
                const int*   __restrict__ idx,
                const float* __restrict__ W,
                const float* __restrict__ bias,
                const float* __restrict__ R,
                const float* __restrict__ gam,
                const float* __restrict__ bet,
                const float* __restrict__ rmean,
                const float* __restrict__ rvar,
                float* __restrict__ dst)
{
    constexpr int KP = K + 4;                 // pad keeps float4 alignment, breaks bank patterns
    __shared__ alignas(16) float sA[BR][KP];  // mean-aggregated rows
    __shared__ alignas(16) float sX[BR][KP];  // residual (self) rows

    const int rowBase = blockIdx.x * BR;
    const int tid = threadIdx.x;

    // ---- Phase 1: stage residual rows + 10-neighbor mean rows into LDS ----
    {
        constexpr int CH   = K / 4;       // float4 chunks per feature row
        constexpr int RPAR = 256 / CH;    // rows staged in parallel
        const int c  = tid % CH;
        const int rr = tid / CH;
        for (int r0 = 0; r0 < BR; r0 += RPAR) {
            const int r   = r0 + rr;
            const int row = rowBase + r;
            const float4 xv = *(const float4*)(src + (size_t)row * K + 4 * c);
            const int p0 = ptr[row], p1 = ptr[row + 1];
            float sx = 0.f, sy = 0.f, sz = 0.f, sw = 0.f;
            for (int p = p0; p < p1; ++p) {
                const int n = idx[p];
                const float4 v = *(const float4*)(src + (size_t)n * K + 4 * c);
                sx += v.x; sy += v.y; sz += v.z; sw += v.w;
            }
            const float inv = 1.0f / (float)(p1 - p0);
            *(float4*)(&sA[r][4 * c]) = make_float4(sx * inv, sy * inv, sz * inv, sw * inv);
            *(float4*)(&sX[r][4 * c]) = xv;
        }
    }
    __syncthreads();

    const int tx = tid % 64;
    const int ty = tid / 64;

    if constexpr (NOUT == 256) {
        // ---- Phase 2: register-tiled GEMM, thread tile = 8 rows x 4 cols ----
        float accW[8][4];
        float accR[8][4];
        #pragma unroll
        for (int r = 0; r < 8; ++r)
            #pragma unroll
            for (int j = 0; j < 4; ++j) { accW[r][j] = 0.f; accR[r][j] = 0.f; }

        for (int k = 0; k < K; k += 4) {
            float wv[4][4], rw[4][4];
            #pragma unroll
            for (int q = 0; q < 4; ++q) {
                *(float4*)wv[q] = *(const float4*)(W + (size_t)(k + q) * NOUT + 4 * tx);
                *(float4*)rw[q] = *(const float4*)(R + (size_t)(k + q) * NOUT + 4 * tx);
            }
            #pragma unroll
            for (int r = 0; r < 8; ++r) {
                float av[4], xv[4];
                *(float4*)av = *(const float4*)(&sA[8 * ty + r][k]);
                *(float4*)xv = *(const float4*)(&sX[8 * ty + r][k]);
                #pragma unroll
                for (int j = 0; j < 4; ++j) {
                    float aw = accW[r][j], ar = accR[r][j];
                    #pragma unroll
                    for (int q = 0; q < 4; ++q) {
                        aw += av[q] * wv[q][j];
                        ar += xv[q] * rw[q][j];
                    }
                    accW[r][j] = aw; accR[r][j] = ar;
                }
            }
        }

        // ---- Epilogue: bias + BN(eval) + ReLU, coalesced float4 store ----
        const int col = 4 * tx;
        float sc[4], sh[4], bb[4];
        #pragma unroll
        for (int j = 0; j < 4; ++j) {
            const float scale = gam[col + j] * rsqrtf(rvar[col + j] + BN_EPS);
            sc[j] = scale;
            sh[j] = bet[col + j] - rmean[col + j] * scale;
            bb[j] = bias[col + j];
        }
        #pragma unroll
        for (int r = 0; r < 8; ++r) {
            const int row = rowBase + 8 * ty + r;
            float o[4];
            #pragma unroll
            for (int j = 0; j < 4; ++j) {
                float h = accW[r][j] + accR[r][j] + bb[j];
                h = h * sc[j] + sh[j];
                o[j] = fmaxf(h, 0.f);
            }
            *(float4*)(dst + (size_t)row * NOUT + col) = *(const float4*)o;
        }
    } else {
        // ---- NOUT == 47: thread tile = 8 rows x 1 col, log_softmax epilogue ----
        const bool valid = (tx < NOUT);
        float acc[8];
        #pragma unroll
        for (int r = 0; r < 8; ++r) acc[r] = 0.f;

        for (int k = 0; k < K; k += 4) {
            float wv[4], rw[4];
            #pragma unroll
            for (int q = 0; q < 4; ++q) {
                wv[q] = valid ? W[(size_t)(k + q) * NOUT + tx] : 0.f;
                rw[q] = valid ? R[(size_t)(k + q) * NOUT + tx] : 0.f;
            }
            #pragma unroll
            for (int r = 0; r < 8; ++r) {
                float av[4], xv[4];
                *(float4*)av = *(const float4*)(&sA[8 * ty + r][k]);
                *(float4*)xv = *(const float4*)(&sX[8 * ty + r][k]);
                float a = acc[r];
                #pragma unroll
                for (int q = 0; q < 4; ++q) a += av[q] * wv[q] + xv[q] * rw[q];
                acc[r] = a;
            }
        }

        #pragma unroll
        for (int r = 0; r < 8; ++r) {
            const int row = rowBase + 8 * ty + r;
            float logit = valid ? acc[r] + bias[tx] : -3.0e38f;
            float m = logit;
            #pragma unroll
            for (int o = 32; o > 0; o >>= 1) m = fmaxf(m, __shfl_xor(m, o, 64));
            const float e = valid ? expf(logit - m) : 0.f;
            float s = e;
            #pragma unroll
            for (int o = 32; o > 0; o >>= 1) s += __shfl_xor(s, o, 64);
            if (valid) dst[(size_t)row * NOUT + tx] = (logit - m) - logf(s);
        }
    }
}

extern "C" void kernel_launch(void* const* d_in, const int* in_sizes, int n_in,
                              void* d_out, int out_size, void* d_ws, size_t ws_size,
                              hipStream_t stream)
{
    const float* x   = (const float*)d_in[0];
    const int*   ptr = (const int*)d_in[1];
    const int*   idx = (const int*)d_in[2];
    const float* W0  = (const float*)d_in[3];
    const float* b0  = (const float*)d_in[4];
    const float* R0  = (const float*)d_in[5];
    const float* W1  = (const float*)d_in[6];
    const float* b1  = (const float*)d_in[7];
    const float* R1  = (const float*)d_in[8];
    const float* W2  = (const float*)d_in[9];
    const float* b2  = (const float*)d_in[10];
    const float* R2  = (const float*)d_in[11];
    const float* g0  = (const float*)d_in[12];
    const float* be0 = (const float*)d_in[13];
    const float* rm0 = (const float*)d_in[14];
    const float* rv0 = (const float*)d_in[15];
    const float* g1  = (const float*)d_in[16];
    const float* be1 = (const float*)d_in[17];
    const float* rm1 = (const float*)d_in[18];
    const float* rv1 = (const float*)d_in[19];

    float* out = (float*)d_out;
    float* h0  = (float*)d_ws;                       // [20000, 256]
    float* h1  = h0 + (size_t)ROWS * 256;            // [20000, 256]

    dim3 grid(ROWS / BR), blk(256);
    sage_layer<128, 256, true ><<<grid, blk, 0, stream>>>(x,  ptr, idx, W0, b0, R0, g0, be0, rm0, rv0, h0);
    sage_layer<256, 256, true ><<<grid, blk, 0, stream>>>(h0, ptr, idx, W1, b1, R1, g1, be1, rm1, rv1, h1);
    sage_layer<256, 47,  false><<<grid, blk, 0, stream>>>(h1, ptr, idx, W2, b2, R2, nullptr, nullptr, nullptr, nullptr, out);
}

// Round 2
// 159.545 us; speedup vs baseline: 2.4174x; 2.4174x over previous
//
#include <hip/hip_runtime.h>
#include <cmath>

// HistorySAGE: 3 fused GraphSAGE layers, 20000 live rows each (idx < 20000,
// output rows < 20000). GEMM phase on bf16 MFMA; aggregation staged to LDS.
constexpr int ROWS = 20000;
constexpr float BN_EPS = 1e-5f;

using f32x4  = __attribute__((ext_vector_type(4))) float;
using short8 = __attribute__((ext_vector_type(8))) short;

__device__ __forceinline__ float bf2f(unsigned short u) {
    unsigned int x = ((unsigned int)u) << 16;
    return __builtin_bit_cast(float, x);
}
__device__ __forceinline__ unsigned short f2bf(float f) {
    unsigned int x = __builtin_bit_cast(unsigned int, f);
    unsigned int r = x + 0x7fffu + ((x >> 16) & 1u);   // RNE
    return (unsigned short)(r >> 16);
}

// Build Bcat[n][kk] bf16, kk<K -> W[kk][n], else R[kk-K][n]; n>=Ntrue -> 0.
__global__ void conv_weights(const float* __restrict__ W, const float* __restrict__ R,
                             unsigned short* __restrict__ B, int K, int Ntrue, int Npad)
{
    const int Kt = 2 * K;
    const int e = blockIdx.x * blockDim.x + threadIdx.x;
    if (e >= Npad * Kt) return;
    const int n = e / Kt, kk = e % Kt;
    float v = 0.f;
    if (n < Ntrue) v = (kk < K) ? W[(size_t)kk * Ntrue + n] : R[(size_t)(kk - K) * Ntrue + n];
    B[e] = f2bf(v);
}

// MODE 0: N==256, BM==32, 4 waves x (32 rows x 64 cols), BN+ReLU -> bf16 dst.
// MODE 1: N==48 (true 47), BM==64, 4 waves x (16 rows x 48 cols), log_softmax -> f32.
template<int K, int N, int BM, int MODE, bool SRC_BF16>
__global__ __launch_bounds__(256)
void sage_mfma(const float* __restrict__ srcF,
               const unsigned short* __restrict__ srcB,
               const int* __restrict__ ptr,
               const int* __restrict__ idx,
               const unsigned short* __restrict__ Bcat,
               const float* __restrict__ bias,
               const float* __restrict__ gam,
               const float* __restrict__ bet,
               const float* __restrict__ rmean,
               const float* __restrict__ rvar,
               unsigned short* __restrict__ dstB,
               float* __restrict__ dstF)
{
    constexpr int Kt = 2 * K;
    constexpr int KP = Kt + 8;                 // padded stride: 1040/528 B, 16B-aligned, conflict-free
    __shared__ unsigned short sA[BM * KP];

    const int tid = threadIdx.x;
    const int rowBase = blockIdx.x * BM;

    // ---- stage A: 10-neighbor mean rows (coalesced: one row per CA threads) ----
    constexpr int CA = K / 8;
    for (int u = tid; u < BM * CA; u += 256) {
        const int r = u / CA, c = u % CA;
        int row = rowBase + r;
        if (row >= ROWS) row = 0;
        const int p0 = ptr[row], p1 = ptr[row + 1];
        float acc[8];
        #pragma unroll
        for (int j = 0; j < 8; ++j) acc[j] = 0.f;
        for (int p = p0; p < p1; ++p) {
            const int nb = idx[p];
            if constexpr (SRC_BF16) {
                const short8 v = *(const short8*)(srcB + (size_t)nb * K + c * 8);
                #pragma unroll
                for (int j = 0; j < 8; ++j) acc[j] += bf2f((unsigned short)v[j]);
            } else {
                const float4 v0 = *(const float4*)(srcF + (size_t)nb * K + c * 8);
                const float4 v1 = *(const float4*)(srcF + (size_t)nb * K + c * 8 + 4);
                acc[0] += v0.x; acc[1] += v0.y; acc[2] += v0.z; acc[3] += v0.w;
                acc[4] += v1.x; acc[5] += v1.y; acc[6] += v1.z; acc[7] += v1.w;
            }
        }
        const float inv = 1.0f / (float)(p1 - p0);
        short8 o;
        #pragma unroll
        for (int j = 0; j < 8; ++j) o[j] = (short)f2bf(acc[j] * inv);
        *(short8*)(&sA[r * KP + c * 8]) = o;
    }
    // ---- stage B: residual (self) rows ----
    for (int u = tid; u < BM * CA; u += 256) {
        const int r = u / CA, c = u % CA;
        int row = rowBase + r;
        if (row >= ROWS) row = 0;
        short8 o;
        if constexpr (SRC_BF16) {
            o = *(const short8*)(srcB + (size_t)row * K + c * 8);
        } else {
            const float4 v0 = *(const float4*)(srcF + (size_t)row * K + c * 8);
            const float4 v1 = *(const float4*)(srcF + (size_t)row * K + c * 8 + 4);
            o[0] = (short)f2bf(v0.x); o[1] = (short)f2bf(v0.y);
            o[2] = (short)f2bf(v0.z); o[3] = (short)f2bf(v0.w);
            o[4] = (short)f2bf(v1.x); o[5] = (short)f2bf(v1.y);
            o[6] = (short)f2bf(v1.z); o[7] = (short)f2bf(v1.w);
        }
        *(short8*)(&sA[r * KP + K + c * 8]) = o;
    }
    __syncthreads();

    const int lane = tid & 63, wid = tid >> 6;
    const int mrow = lane & 15, kg = (lane >> 4) * 8;

    if constexpr (MODE == 0) {
        f32x4 acc[2][4];
        #pragma unroll
        for (int a = 0; a < 2; ++a)
            #pragma unroll
            for (int t = 0; t < 4; ++t) acc[a][t] = (f32x4){0.f, 0.f, 0.f, 0.f};
        const int ncol0 = wid * 64;
        #pragma unroll
        for (int k0 = 0; k0 < Kt; k0 += 32) {
            const short8 a0 = *(const short8*)(&sA[mrow * KP + k0 + kg]);
            const short8 a1 = *(const short8*)(&sA[(16 + mrow) * KP + k0 + kg]);
            #pragma unroll
            for (int t = 0; t < 4; ++t) {
                const short8 b = *(const short8*)(Bcat + (size_t)(ncol0 + t * 16 + mrow) * Kt + k0 + kg);
                acc[0][t] = __builtin_amdgcn_mfma_f32_16x16x32_bf16(a0, b, acc[0][t], 0, 0, 0);
                acc[1][t] = __builtin_amdgcn_mfma_f32_16x16x32_bf16(a1, b, acc[1][t], 0, 0, 0);
            }
        }
        #pragma unroll
        for (int t = 0; t < 4; ++t) {
            const int col = ncol0 + t * 16 + mrow;
            const float sc = gam[col] * rsqrtf(rvar[col] + BN_EPS);
            const float sh = bet[col] - rmean[col] * sc;
            const float bb = bias[col];
            #pragma unroll
            for (int a = 0; a < 2; ++a)
                #pragma unroll
                for (int reg = 0; reg < 4; ++reg) {
                    const int row = rowBase + a * 16 + (lane >> 4) * 4 + reg;
                    float h = acc[a][t][reg] + bb;
                    h = fmaxf(h * sc + sh, 0.f);
                    dstB[(size_t)row * N + col] = f2bf(h);
                }
        }
    } else {
        f32x4 acc[3];
        #pragma unroll
        for (int t = 0; t < 3; ++t) acc[t] = (f32x4){0.f, 0.f, 0.f, 0.f};
        #pragma unroll
        for (int k0 = 0; k0 < Kt; k0 += 32) {
            const short8 a = *(const short8*)(&sA[(wid * 16 + mrow) * KP + k0 + kg]);
            #pragma unroll
            for (int t = 0; t < 3; ++t) {
                const short8 b = *(const short8*)(Bcat + (size_t)(t * 16 + mrow) * Kt + k0 + kg);
                acc[t] = __builtin_amdgcn_mfma_f32_16x16x32_bf16(a, b, acc[t], 0, 0, 0);
            }
        }
        const int c0 = mrow, c1 = 16 + mrow, c2 = 32 + mrow;
        const float bb0 = bias[c0], bb1 = bias[c1];
        const float bb2 = (c2 < 47) ? bias[c2] : 0.f;
        #pragma unroll
        for (int reg = 0; reg < 4; ++reg) {
            const int grow = rowBase + wid * 16 + (lane >> 4) * 4 + reg;
            const float v0 = acc[0][reg] + bb0;
            const float v1 = acc[1][reg] + bb1;
            const float v2 = (c2 < 47) ? acc[2][reg] + bb2 : -3.0e38f;
            float mx = fmaxf(fmaxf(v0, v1), v2);
            #pragma unroll
            for (int o = 1; o < 16; o <<= 1) mx = fmaxf(mx, __shfl_xor(mx, o, 16));
            float s = expf(v0 - mx) + expf(v1 - mx) + ((c2 < 47) ? expf(v2 - mx) : 0.f);
            #pragma unroll
            for (int o = 1; o < 16; o <<= 1) s += __shfl_xor(s, o, 16);
            const float ls = mx + logf(s);
            if (grow < ROWS) {
                dstF[(size_t)grow * 47 + c0] = v0 - ls;
                dstF[(size_t)grow * 47 + c1] = v1 - ls;
                if (c2 < 47) dstF[(size_t)grow * 47 + c2] = v2 - ls;
            }
        }
    }
}

extern "C" void kernel_launch(void* const* d_in, const int* in_sizes, int n_in,
                              void* d_out, int out_size, void* d_ws, size_t ws_size,
                              hipStream_t stream)
{
    const float* x   = (const float*)d_in[0];
    const int*   ptr = (const int*)d_in[1];
    const int*   idx = (const int*)d_in[2];
    const float* W0  = (const float*)d_in[3];
    const float* b0  = (const float*)d_in[4];
    const float* R0  = (const float*)d_in[5];
    const float* W1  = (const float*)d_in[6];
    const float* b1  = (const float*)d_in[7];
    const float* R1  = (const float*)d_in[8];
    const float* W2  = (const float*)d_in[9];
    const float* b2  = (const float*)d_in[10];
    const float* R2  = (const float*)d_in[11];
    const float* g0  = (const float*)d_in[12];
    const float* be0 = (const float*)d_in[13];
    const float* rm0 = (const float*)d_in[14];
    const float* rv0 = (const float*)d_in[15];
    const float* g1  = (const float*)d_in[16];
    const float* be1 = (const float*)d_in[17];
    const float* rm1 = (const float*)d_in[18];
    const float* rv1 = (const float*)d_in[19];

    char* ws = (char*)d_ws;
    unsigned short* B0 = (unsigned short*)(ws);                    // 256 x 256 bf16 = 128 KB
    unsigned short* B1 = (unsigned short*)(ws + 131072);           // 256 x 512 bf16 = 256 KB
    unsigned short* B2 = (unsigned short*)(ws + 393216);           //  48 x 512 bf16 =  48 KB
    unsigned short* h0 = (unsigned short*)(ws + 442368);           // 20000 x 256 bf16
    unsigned short* h1 = (unsigned short*)(ws + 442368 + 10240000);
    float* out = (float*)d_out;

    conv_weights<<<(256 * 256 + 255) / 256, 256, 0, stream>>>(W0, R0, B0, 128, 256, 256);
    conv_weights<<<(256 * 512 + 255) / 256, 256, 0, stream>>>(W1, R1, B1, 256, 256, 256);
    conv_weights<<<( 48 * 512 + 255) / 256, 256, 0, stream>>>(W2, R2, B2, 256,  47,  48);

    sage_mfma<128, 256, 32, 0, false><<<625, 256, 0, stream>>>(
        x, nullptr, ptr, idx, B0, b0, g0, be0, rm0, rv0, h0, nullptr);
    sage_mfma<256, 256, 32, 0, true ><<<625, 256, 0, stream>>>(
        nullptr, h0, ptr, idx, B1, b1, g1, be1, rm1, rv1, h1, nullptr);
    sage_mfma<256, 48, 64, 1, true ><<<313, 256, 0, stream>>>(
        nullptr, h1, ptr, idx, B2, b2, nullptr, nullptr, nullptr, nullptr, nullptr, out);
}